// Round 1
// baseline (376.823 us; speedup 1.0000x reference)
//
#include <hip/hip_runtime.h>

// HyperNet fused forward, v5.
//   logits = h1 @ (enc_w2 @ comb_top) + h2 @ (pol_w3 @ comb_bot) + (pol_b3 @ comb_bot + comb_b)
//   h1 = relu(enc @ enc_w1) [N,64],  h2 = relu(relu(mean@pol_w1+b1)@pol_w2+b2) [N,32]
//
// v5 changes (R0 of this session):
//   logits: j-split x2 (2048 blocks, 16 rows x 512 cols, float2 acc) -> 2x waves in
//           flight; was latency-bound at 17% occupancy / 47% VALUBusy. logprob via
//           atomicAdd onto buffer pre-initialized in stage1.
//   stage1: h1/h2 rebuilt with 4-rows-per-thread register blocking (8 ds_read_b128 per
//           64 FMA, was 6 per 32) with bank-conflict-free row mapping rg + G*i.
//           h2 (longest blocks) dispatched first.
//   prep:   atomic-free full-K precompute (52 blocks); weights read as wave-uniform
//           scalar loads (SMEM pipe). Kills hipMemsetAsync dispatch + 1.7M atomics.

#define N_CLIENTS 16384
#define P 1024
#define IN_DIM 512
#define SPAD 36   // LDS row stride (floats); (r*36)%32 == (4r)%32 -> conflict-free reads

#define FMA4(acc, a, w0, w1, w2, w3)                                  \
  acc.x = fmaf(a.x, w0.x, acc.x); acc.y = fmaf(a.x, w0.y, acc.y);     \
  acc.z = fmaf(a.x, w0.z, acc.z); acc.w = fmaf(a.x, w0.w, acc.w);     \
  acc.x = fmaf(a.y, w1.x, acc.x); acc.y = fmaf(a.y, w1.y, acc.y);     \
  acc.z = fmaf(a.y, w1.z, acc.z); acc.w = fmaf(a.y, w1.w, acc.w);     \
  acc.x = fmaf(a.z, w2.x, acc.x); acc.y = fmaf(a.z, w2.y, acc.y);     \
  acc.z = fmaf(a.z, w2.z, acc.z); acc.w = fmaf(a.z, w2.w, acc.w);     \
  acc.x = fmaf(a.w, w3.x, acc.x); acc.y = fmaf(a.w, w3.y, acc.y);     \
  acc.z = fmaf(a.w, w3.z, acc.z); acc.w = fmaf(a.w, w3.w, acc.w);

// ---------------------------------------------------------------------------
// stage1 grid (500 blocks):
//   [0,128)   h2: 128 rows/block, K=1024, 4 rows x 4 cols per thread
//   [128,384) h1: 64 rows/block,  K=512,  4 rows x 4 cols per thread
//   [384,436) fused-weight precompute (full-K, no atomics)
//   [436,500) out_logprob / out_entropy constant fill
// ---------------------------------------------------------------------------
__global__ __launch_bounds__(256) void stage1(
    const float* __restrict__ encoding,  // [N][512]
    const float* __restrict__ mean,      // [N][1024]
    const float* __restrict__ enc_w1,    // [512][64]
    const float* __restrict__ pol_w1,    // [1024][32]
    const float* __restrict__ pol_b1,    // [32]
    const float* __restrict__ pol_w2,    // [32][32]
    const float* __restrict__ pol_b2,    // [32]
    const float* __restrict__ enc_w2,    // [64][1024]
    const float* __restrict__ pol_w3,    // [32][1024]
    const float* __restrict__ pol_b3,    // [1024]
    const float* __restrict__ comb_w,    // [2048][1024]
    const float* __restrict__ comb_b,    // [1024]
    float* __restrict__ h1h2,            // [N][96]
    float* __restrict__ fused,           // [97][1024] (fully written here)
    float* __restrict__ out_logprob,     // [N] (init to const)
    float* __restrict__ out_entropy)     // [N]
{
    __shared__ __attribute__((aligned(16))) float smem[128 * SPAD + 32 * SPAD]; // 23 KB
    const int t = threadIdx.x;
    const int bid = blockIdx.x;

    if (bid < 128) {
        // ---- h2: 128 rows x 32 cols, K=1024 in 32 tiles of 32; then layer2 in-block.
        float* sA = smem;                  // [128][SPAD]
        float* sW = smem + 128 * SPAD;     // [32][SPAD]
        const long r0 = (long)bid * 128;
        const int colq = t & 7, c0 = colq * 4;
        const int rg = t >> 3;             // 0..31; thread owns rows rg + {0,32,64,96}
        const float* aSrc = mean + (r0 + rg) * P + c0;     // k-seg = c0 within tile
        const float* wSrc = pol_w1 + rg * 32 + c0;

        float4 aR0 = *(const float4*)(aSrc);
        float4 aR1 = *(const float4*)(aSrc + 32 * P);
        float4 aR2 = *(const float4*)(aSrc + 64 * P);
        float4 aR3 = *(const float4*)(aSrc + 96 * P);
        float4 wR  = *(const float4*)(wSrc);
        float4 acc0 = {0.f,0.f,0.f,0.f}, acc1 = {0.f,0.f,0.f,0.f};
        float4 acc2 = {0.f,0.f,0.f,0.f}, acc3 = {0.f,0.f,0.f,0.f};

        for (int kt = 0; kt < 32; ++kt) {
            __syncthreads();
            *(float4*)(sA + (rg +  0) * SPAD + c0) = aR0;
            *(float4*)(sA + (rg + 32) * SPAD + c0) = aR1;
            *(float4*)(sA + (rg + 64) * SPAD + c0) = aR2;
            *(float4*)(sA + (rg + 96) * SPAD + c0) = aR3;
            *(float4*)(sW + rg * SPAD + c0) = wR;
            __syncthreads();
            if (kt < 31) {
                const int ko = (kt + 1) * 32;
                aR0 = *(const float4*)(aSrc + ko);
                aR1 = *(const float4*)(aSrc + 32 * P + ko);
                aR2 = *(const float4*)(aSrc + 64 * P + ko);
                aR3 = *(const float4*)(aSrc + 96 * P + ko);
                wR  = *(const float4*)(wSrc + (kt + 1) * 32 * 32);
            }
            #pragma unroll
            for (int k4 = 0; k4 < 8; ++k4) {
                const float4 a0 = *(const float4*)(sA + (rg +  0) * SPAD + k4 * 4);
                const float4 a1 = *(const float4*)(sA + (rg + 32) * SPAD + k4 * 4);
                const float4 a2 = *(const float4*)(sA + (rg + 64) * SPAD + k4 * 4);
                const float4 a3 = *(const float4*)(sA + (rg + 96) * SPAD + k4 * 4);
                const float4 w0 = *(const float4*)(sW + (k4 * 4 + 0) * SPAD + c0);
                const float4 w1 = *(const float4*)(sW + (k4 * 4 + 1) * SPAD + c0);
                const float4 w2 = *(const float4*)(sW + (k4 * 4 + 2) * SPAD + c0);
                const float4 w3 = *(const float4*)(sW + (k4 * 4 + 3) * SPAD + c0);
                FMA4(acc0, a0, w0, w1, w2, w3);
                FMA4(acc1, a1, w0, w1, w2, w3);
                FMA4(acc2, a2, w0, w1, w2, w3);
                FMA4(acc3, a3, w0, w1, w2, w3);
            }
        }
        // layer 2: t1 = relu(acc + b1) -> sA; pol_w2 -> sW
        __syncthreads();
        {
            const float4 b1v = *(const float4*)(pol_b1 + c0);
            float4 t0, t1, t2, t3;
            t0.x = fmaxf(acc0.x + b1v.x, 0.f); t0.y = fmaxf(acc0.y + b1v.y, 0.f);
            t0.z = fmaxf(acc0.z + b1v.z, 0.f); t0.w = fmaxf(acc0.w + b1v.w, 0.f);
            t1.x = fmaxf(acc1.x + b1v.x, 0.f); t1.y = fmaxf(acc1.y + b1v.y, 0.f);
            t1.z = fmaxf(acc1.z + b1v.z, 0.f); t1.w = fmaxf(acc1.w + b1v.w, 0.f);
            t2.x = fmaxf(acc2.x + b1v.x, 0.f); t2.y = fmaxf(acc2.y + b1v.y, 0.f);
            t2.z = fmaxf(acc2.z + b1v.z, 0.f); t2.w = fmaxf(acc2.w + b1v.w, 0.f);
            t3.x = fmaxf(acc3.x + b1v.x, 0.f); t3.y = fmaxf(acc3.y + b1v.y, 0.f);
            t3.z = fmaxf(acc3.z + b1v.z, 0.f); t3.w = fmaxf(acc3.w + b1v.w, 0.f);
            *(float4*)(sA + (rg +  0) * SPAD + c0) = t0;
            *(float4*)(sA + (rg + 32) * SPAD + c0) = t1;
            *(float4*)(sA + (rg + 64) * SPAD + c0) = t2;
            *(float4*)(sA + (rg + 96) * SPAD + c0) = t3;
        }
        *(float4*)(sW + rg * SPAD + c0) = *(const float4*)(pol_w2 + rg * 32 + c0);
        __syncthreads();

        float4 d0 = {0.f,0.f,0.f,0.f}, d1 = {0.f,0.f,0.f,0.f};
        float4 d2 = {0.f,0.f,0.f,0.f}, d3 = {0.f,0.f,0.f,0.f};
        #pragma unroll
        for (int k4 = 0; k4 < 8; ++k4) {
            const float4 a0 = *(const float4*)(sA + (rg +  0) * SPAD + k4 * 4);
            const float4 a1 = *(const float4*)(sA + (rg + 32) * SPAD + k4 * 4);
            const float4 a2 = *(const float4*)(sA + (rg + 64) * SPAD + k4 * 4);
            const float4 a3 = *(const float4*)(sA + (rg + 96) * SPAD + k4 * 4);
            const float4 w0 = *(const float4*)(sW + (k4 * 4 + 0) * SPAD + c0);
            const float4 w1 = *(const float4*)(sW + (k4 * 4 + 1) * SPAD + c0);
            const float4 w2 = *(const float4*)(sW + (k4 * 4 + 2) * SPAD + c0);
            const float4 w3 = *(const float4*)(sW + (k4 * 4 + 3) * SPAD + c0);
            FMA4(d0, a0, w0, w1, w2, w3);
            FMA4(d1, a1, w0, w1, w2, w3);
            FMA4(d2, a2, w0, w1, w2, w3);
            FMA4(d3, a3, w0, w1, w2, w3);
        }
        const float4 b2v = *(const float4*)(pol_b2 + c0);
        float4 o;
        o.x = fmaxf(d0.x + b2v.x, 0.f); o.y = fmaxf(d0.y + b2v.y, 0.f);
        o.z = fmaxf(d0.z + b2v.z, 0.f); o.w = fmaxf(d0.w + b2v.w, 0.f);
        *(float4*)(h1h2 + (r0 + rg +  0) * 96 + 64 + c0) = o;
        o.x = fmaxf(d1.x + b2v.x, 0.f); o.y = fmaxf(d1.y + b2v.y, 0.f);
        o.z = fmaxf(d1.z + b2v.z, 0.f); o.w = fmaxf(d1.w + b2v.w, 0.f);
        *(float4*)(h1h2 + (r0 + rg + 32) * 96 + 64 + c0) = o;
        o.x = fmaxf(d2.x + b2v.x, 0.f); o.y = fmaxf(d2.y + b2v.y, 0.f);
        o.z = fmaxf(d2.z + b2v.z, 0.f); o.w = fmaxf(d2.w + b2v.w, 0.f);
        *(float4*)(h1h2 + (r0 + rg + 64) * 96 + 64 + c0) = o;
        o.x = fmaxf(d3.x + b2v.x, 0.f); o.y = fmaxf(d3.y + b2v.y, 0.f);
        o.z = fmaxf(d3.z + b2v.z, 0.f); o.w = fmaxf(d3.w + b2v.w, 0.f);
        *(float4*)(h1h2 + (r0 + rg + 96) * 96 + 64 + c0) = o;
    } else if (bid < 384) {
        // ---- h1: 64 rows x 64 cols, K=512 in 16 tiles of 32.
        float* sA = smem;                 // [64][SPAD]
        float* sW = smem + 64 * SPAD;     // [32][64]
        const long r0 = (long)(bid - 128) * 64;
        const int colq = t & 15, c0 = colq * 4;
        const int rg = t >> 4;            // 0..15; thread owns rows rg + {0,16,32,48}
        const int arow = t >> 3, aseg = t & 7;
        const float* aSrc = encoding + (r0 + arow) * IN_DIM + aseg * 4;
        const float* wSrc = enc_w1 + (t >> 4) * 64 + c0;

        float4 aR0 = *(const float4*)(aSrc);
        float4 aR1 = *(const float4*)(aSrc + 32 * IN_DIM);
        float4 wR0 = *(const float4*)(wSrc);
        float4 wR1 = *(const float4*)(wSrc + 16 * 64);
        float4 acc0 = {0.f,0.f,0.f,0.f}, acc1 = {0.f,0.f,0.f,0.f};
        float4 acc2 = {0.f,0.f,0.f,0.f}, acc3 = {0.f,0.f,0.f,0.f};

        for (int kt = 0; kt < 16; ++kt) {
            __syncthreads();
            *(float4*)(sA + arow * SPAD + aseg * 4) = aR0;
            *(float4*)(sA + (arow + 32) * SPAD + aseg * 4) = aR1;
            *(float4*)(sW + (t >> 4) * 64 + c0) = wR0;
            *(float4*)(sW + ((t >> 4) + 16) * 64 + c0) = wR1;
            __syncthreads();
            if (kt < 15) {
                aR0 = *(const float4*)(aSrc + (kt + 1) * 32);
                aR1 = *(const float4*)(aSrc + 32 * IN_DIM + (kt + 1) * 32);
                wR0 = *(const float4*)(wSrc + (kt + 1) * 2048);
                wR1 = *(const float4*)(wSrc + 16 * 64 + (kt + 1) * 2048);
            }
            #pragma unroll
            for (int k4 = 0; k4 < 8; ++k4) {
                const float4 a0 = *(const float4*)(sA + (rg +  0) * SPAD + k4 * 4);
                const float4 a1 = *(const float4*)(sA + (rg + 16) * SPAD + k4 * 4);
                const float4 a2 = *(const float4*)(sA + (rg + 32) * SPAD + k4 * 4);
                const float4 a3 = *(const float4*)(sA + (rg + 48) * SPAD + k4 * 4);
                const float4 w0 = *(const float4*)(sW + (k4 * 4 + 0) * 64 + c0);
                const float4 w1 = *(const float4*)(sW + (k4 * 4 + 1) * 64 + c0);
                const float4 w2 = *(const float4*)(sW + (k4 * 4 + 2) * 64 + c0);
                const float4 w3 = *(const float4*)(sW + (k4 * 4 + 3) * 64 + c0);
                FMA4(acc0, a0, w0, w1, w2, w3);
                FMA4(acc1, a1, w0, w1, w2, w3);
                FMA4(acc2, a2, w0, w1, w2, w3);
                FMA4(acc3, a3, w0, w1, w2, w3);
            }
        }
        float4 o;
        o.x = fmaxf(acc0.x, 0.f); o.y = fmaxf(acc0.y, 0.f);
        o.z = fmaxf(acc0.z, 0.f); o.w = fmaxf(acc0.w, 0.f);
        *(float4*)(h1h2 + (r0 + rg +  0) * 96 + c0) = o;
        o.x = fmaxf(acc1.x, 0.f); o.y = fmaxf(acc1.y, 0.f);
        o.z = fmaxf(acc1.z, 0.f); o.w = fmaxf(acc1.w, 0.f);
        *(float4*)(h1h2 + (r0 + rg + 16) * 96 + c0) = o;
        o.x = fmaxf(acc2.x, 0.f); o.y = fmaxf(acc2.y, 0.f);
        o.z = fmaxf(acc2.z, 0.f); o.w = fmaxf(acc2.w, 0.f);
        *(float4*)(h1h2 + (r0 + rg + 32) * 96 + c0) = o;
        o.x = fmaxf(acc3.x, 0.f); o.y = fmaxf(acc3.y, 0.f);
        o.z = fmaxf(acc3.z, 0.f); o.w = fmaxf(acc3.w, 0.f);
        *(float4*)(h1h2 + (r0 + rg + 48) * 96 + c0) = o;
    } else if (bid < 436) {
        // ---- fused-weight precompute, full-K, no atomics. pid -> (j-chunk, row-group)
        const int pid = bid - 384;          // [0, 52)
        const int jc = pid & 3;
        const int by = pid >> 2;            // [0, 13)
        const int j = jc * 256 + t;

        if (by < 12) {
            const float* wsrc = (by < 8) ? (enc_w2 + by * 8 * 1024)
                                         : (pol_w3 + (by - 8) * 8 * 1024);
            const int kbase   = (by < 8) ? 0 : 1024;
            const int outbase = (by < 8) ? by * 8 : 64 + (by - 8) * 8;
            const float* cw = comb_w + (size_t)kbase * 1024 + j;
            float acc[8];
            #pragma unroll
            for (int r = 0; r < 8; ++r) acc[r] = 0.f;
            #pragma unroll 4
            for (int k = 0; k < 1024; ++k) {
                const float c = cw[(size_t)k * 1024];
                #pragma unroll
                for (int r = 0; r < 8; ++r)
                    acc[r] = fmaf(wsrc[r * 1024 + k], c, acc[r]);  // wave-uniform -> s_load
            }
            #pragma unroll
            for (int r = 0; r < 8; ++r)
                fused[(outbase + r) * 1024 + j] = acc[r];
        } else {
            const float* cw = comb_w + (size_t)1024 * 1024 + j;
            float acc = 0.f;
            #pragma unroll 4
            for (int k = 0; k < 1024; ++k)
                acc = fmaf(pol_b3[k], cw[(size_t)k * 1024], acc);
            fused[96 * 1024 + j] = acc + comb_b[j];
        }
    } else {
        // ---- constant fill for logprob (atomic target) and entropy
        const int idx = (bid - 436) * 256 + t;   // 64 blocks * 256 = 16384 exactly
        out_logprob[idx] = 592.8218660580586f;
        out_entropy[idx] = -80.82186605805855f;
    }
}

// ---------------------------------------------------------------------------
// logits + epilogue, j-split x2. Block = 16 rows x 512 cols; thread = 16 rows x
// 2 contiguous cols (float2 acc). w register-dbuf one k4 ahead. logprob partial
// sums via atomicAdd onto the stage1-initialized constant.
// ---------------------------------------------------------------------------
__global__ __launch_bounds__(256) void logits_ep(
    const float* __restrict__ h1h2,    // [N][96]
    const float* __restrict__ fused,   // [97][1024]
    const float* __restrict__ eps,     // [N][1024]
    float* __restrict__ out_sample,    // [N][1024]
    float* __restrict__ out_logprob)   // [N]
{
    __shared__ __attribute__((aligned(16))) float sH[16 * 96];   // 6 KB
    __shared__ float s_red[16][4];
    const int t = threadIdx.x;
    const int rb = blockIdx.x >> 1;
    const int jh = blockIdx.x & 1;
    const long r0 = (long)rb * 16;

    {
        const float4* src = (const float4*)(h1h2 + r0 * 96);
        float4* dst = (float4*)sH;
        dst[t] = src[t];
        if (t < 128) dst[256 + t] = src[256 + t];
    }
    __syncthreads();

    const int j0 = jh * 512 + t * 2;
    const float* fj = fused + j0;

    float2 acc[16];
    {
        const float2 b = *(const float2*)(fj + 96 * 1024);
        #pragma unroll
        for (int r = 0; r < 16; ++r) acc[r] = b;
    }

    float2 wc0 = *(const float2*)(fj);
    float2 wc1 = *(const float2*)(fj + 1024);
    float2 wc2 = *(const float2*)(fj + 2048);
    float2 wc3 = *(const float2*)(fj + 3072);

    for (int k4 = 0; k4 < 24; ++k4) {
        const int kn = (k4 < 23) ? (k4 + 1) * 4 : 92;   // last-iter dummy prefetch
        const float* fn = fj + (size_t)kn * 1024;
        const float2 wn0 = *(const float2*)(fn);
        const float2 wn1 = *(const float2*)(fn + 1024);
        const float2 wn2 = *(const float2*)(fn + 2048);
        const float2 wn3 = *(const float2*)(fn + 3072);
        #pragma unroll
        for (int r = 0; r < 16; ++r) {
            const float4 h = *(const float4*)(sH + r * 96 + k4 * 4);  // broadcast
            acc[r].x = fmaf(h.x, wc0.x, acc[r].x);
            acc[r].y = fmaf(h.x, wc0.y, acc[r].y);
            acc[r].x = fmaf(h.y, wc1.x, acc[r].x);
            acc[r].y = fmaf(h.y, wc1.y, acc[r].y);
            acc[r].x = fmaf(h.z, wc2.x, acc[r].x);
            acc[r].y = fmaf(h.z, wc2.y, acc[r].y);
            acc[r].x = fmaf(h.w, wc3.x, acc[r].x);
            acc[r].y = fmaf(h.w, wc3.y, acc[r].y);
        }
        wc0 = wn0; wc1 = wn1; wc2 = wn2; wc3 = wn3;
    }

    float sq[16];
    const float* ep = eps + r0 * P + j0;
    float* sp = out_sample + r0 * P + j0;
    #pragma unroll
    for (int r = 0; r < 16; ++r) {
        const float m0 = 1.f / (1.f + __expf(-acc[r].x));
        const float m1 = 1.f / (1.f + __expf(-acc[r].y));
        const float2 e = *(const float2*)(ep + r * P);
        const float s0 = fminf(fmaxf(fmaf(0.22360679774997896f, e.x, m0), 0.f), 1.f);
        const float s1 = fminf(fmaxf(fmaf(0.22360679774997896f, e.y, m1), 0.f), 1.f);
        *(float2*)(sp + r * P) = make_float2(s0, s1);
        const float d0 = s0 - m0, d1 = s1 - m1;
        sq[r] = fmaf(d0, d0, d1 * d1);
    }
    #pragma unroll
    for (int r = 0; r < 16; ++r) {
        float v = sq[r];
        v += __shfl_xor(v, 1);
        v += __shfl_xor(v, 2);
        v += __shfl_xor(v, 4);
        v += __shfl_xor(v, 8);
        v += __shfl_xor(v, 16);
        v += __shfl_xor(v, 32);
        if ((t & 63) == 0) s_red[r][t >> 6] = v;
    }
    __syncthreads();
    if (t < 16) {
        const float v = s_red[t][0] + s_red[t][1] + s_red[t][2] + s_red[t][3];
        atomicAdd(&out_logprob[r0 + t], -10.f * v);
    }
}

extern "C" void kernel_launch(void* const* d_in, const int* in_sizes, int n_in,
                              void* d_out, int out_size, void* d_ws, size_t ws_size,
                              hipStream_t stream) {
    const float* encoding = (const float*)d_in[0];
    const float* mean     = (const float*)d_in[1];
    const float* enc_w1   = (const float*)d_in[2];
    const float* enc_w2   = (const float*)d_in[3];
    const float* pol_w1   = (const float*)d_in[4];
    const float* pol_b1   = (const float*)d_in[5];
    const float* pol_w2   = (const float*)d_in[6];
    const float* pol_b2   = (const float*)d_in[7];
    const float* pol_w3   = (const float*)d_in[8];
    const float* pol_b3   = (const float*)d_in[9];
    const float* comb_w   = (const float*)d_in[10];
    const float* comb_b   = (const float*)d_in[11];
    const float* eps      = (const float*)d_in[12];

    float* fused = (float*)d_ws;                          // 97*1024 floats
    float* h1h2  = fused + 97 * 1024;                     // 16384*96 floats
    float* out_sample  = (float*)d_out;
    float* out_logprob = out_sample + (size_t)N_CLIENTS * P;
    float* out_entropy = out_logprob + N_CLIENTS;

    stage1<<<500, 256, 0, stream>>>(encoding, mean, enc_w1, pol_w1, pol_b1,
                                    pol_w2, pol_b2, enc_w2, pol_w3, pol_b3,
                                    comb_w, comb_b, h1h2, fused,
                                    out_logprob, out_entropy);

    logits_ep<<<N_CLIENTS / 16 * 2, 256, 0, stream>>>(
        h1h2, fused, eps, out_sample, out_logprob);
}

// Round 2
// 285.964 us; speedup vs baseline: 1.3177x; 1.3177x over previous
//
#include <hip/hip_runtime.h>

// HyperNet fused forward, v6.
//   logits = h1 @ (enc_w2 @ comb_top) + h2 @ (pol_w3 @ comb_bot) + (pol_b3 @ comb_bot + comb_b)
//   h1 = relu(enc @ enc_w1) [N,64],  h2 = relu(relu(mean@pol_w1+b1)@pol_w2+b2) [N,32]
//
// R1 post-mortem fixes:
//   stage1: R0's 500-block grid was a load-imbalance tail (158us, 6.6% occ). v6 keeps the
//           ratio-8 register blocking but on 128-thread blocks: h2=256 blocks x 64 rows,
//           h1=512 blocks x 32 rows, precompute k-split x4 (416 blocks, first) -> 1184 blocks.
//   logits: sH broadcast ds_reads were the floor (384 b128/thread ~ 61us of LDS pipe).
//           h now lives in 12 VGPRs/lane (loaded direct from global) and is broadcast via
//           v_readlane (VALU pipe, SGPR operand) -> LDS eliminated from the GEMM.
//           8-row blocks (2048), full 1024-col row per block -> no atomics.

#define N_CLIENTS 16384
#define P 1024
#define IN_DIM 512
#define SPAD 36   // LDS row stride (floats): 36%8 pattern stays <=2-way per quarter-wave

#define FMA4(acc, a, w0, w1, w2, w3)                                  \
  acc.x = fmaf(a.x, w0.x, acc.x); acc.y = fmaf(a.x, w0.y, acc.y);     \
  acc.z = fmaf(a.x, w0.z, acc.z); acc.w = fmaf(a.x, w0.w, acc.w);     \
  acc.x = fmaf(a.y, w1.x, acc.x); acc.y = fmaf(a.y, w1.y, acc.y);     \
  acc.z = fmaf(a.y, w1.z, acc.z); acc.w = fmaf(a.y, w1.w, acc.w);     \
  acc.x = fmaf(a.z, w2.x, acc.x); acc.y = fmaf(a.z, w2.y, acc.y);     \
  acc.z = fmaf(a.z, w2.z, acc.z); acc.w = fmaf(a.z, w2.w, acc.w);     \
  acc.x = fmaf(a.w, w3.x, acc.x); acc.y = fmaf(a.w, w3.y, acc.y);     \
  acc.z = fmaf(a.w, w3.z, acc.z); acc.w = fmaf(a.w, w3.w, acc.w);

// ---------------------------------------------------------------------------
// stage1 grid (1184 blocks x 128 threads):
//   [0,416)     fused-weight precompute, k-split x4, atomicAdd (fused pre-zeroed)
//   [416,672)   h2: 64 rows/block, K=1024, thread = 4 rows x 4 cols
//   [672,1184)  h1: 32 rows/block, K=512,  thread = 4 rows x 4 cols
// ---------------------------------------------------------------------------
__global__ __launch_bounds__(128) void stage1(
    const float* __restrict__ encoding,  // [N][512]
    const float* __restrict__ mean,      // [N][1024]
    const float* __restrict__ enc_w1,    // [512][64]
    const float* __restrict__ pol_w1,    // [1024][32]
    const float* __restrict__ pol_b1,    // [32]
    const float* __restrict__ pol_w2,    // [32][32]
    const float* __restrict__ pol_b2,    // [32]
    const float* __restrict__ enc_w2,    // [64][1024]
    const float* __restrict__ pol_w3,    // [32][1024]
    const float* __restrict__ pol_b3,    // [1024]
    const float* __restrict__ comb_w,    // [2048][1024]
    const float* __restrict__ comb_b,    // [1024]
    float* __restrict__ h1h2,            // [N][96]
    float* __restrict__ fused)           // [97][1024] (pre-zeroed by memset)
{
    __shared__ __attribute__((aligned(16))) float smem[64 * SPAD + 32 * 32]; // 13.3 KB
    const int t = threadIdx.x;
    const int bid = blockIdx.x;

    if (bid < 416) {
        // ---- fused-weight precompute: pid -> (j-chunk of 128, row-group, k-chunk of 256)
        const int pid = bid;
        const int jc = pid & 7;
        const int rest = pid >> 3;          // [0, 52)
        const int by = rest % 13;
        const int kz = rest / 13;           // [0, 4)
        const int j = jc * 128 + t;

        if (by < 12) {
            const float* wsrc = (by < 8) ? (enc_w2 + by * 8 * 1024)
                                         : (pol_w3 + (by - 8) * 8 * 1024);
            const int kbase   = (by < 8) ? 0 : 1024;
            const int outbase = (by < 8) ? by * 8 : 64 + (by - 8) * 8;
            const float* cw = comb_w + ((size_t)kbase + kz * 256) * 1024 + j;
            float acc[8];
            #pragma unroll
            for (int r = 0; r < 8; ++r) acc[r] = 0.f;
            #pragma unroll 4
            for (int k = 0; k < 256; ++k) {
                const float c = cw[(size_t)k * 1024];
                #pragma unroll
                for (int r = 0; r < 8; ++r)
                    acc[r] = fmaf(wsrc[r * 1024 + kz * 256 + k], c, acc[r]);  // uniform -> s_load
            }
            #pragma unroll
            for (int r = 0; r < 8; ++r)
                atomicAdd(&fused[(outbase + r) * 1024 + j], acc[r]);
        } else {
            const float* cw = comb_w + ((size_t)1024 + kz * 256) * 1024 + j;
            float acc = 0.f;
            #pragma unroll 4
            for (int k = 0; k < 256; ++k)
                acc = fmaf(pol_b3[kz * 256 + k], cw[(size_t)k * 1024], acc);
            atomicAdd(&fused[96 * 1024 + j], acc + (kz == 0 ? comb_b[j] : 0.f));
        }
    } else if (bid < 672) {
        // ---- h2: 64 rows x 32 cols, K=1024 in 32 tiles of 32; then layer2 in-block.
        float* sA = smem;                  // [64][SPAD]
        float* sW = smem + 64 * SPAD;      // [32][32]
        const long r0 = (long)(bid - 416) * 64;
        const int c0 = (t & 7) * 4;
        const int rg = t >> 3;             // 0..15; rows rg + {0,16,32,48}
        const int arow = t >> 3, aseg = t & 7;
        const float* aSrc = mean + (r0 + arow) * P + aseg * 4;
        const float* wSrc = pol_w1 + arow * 32 + aseg * 4;

        float4 aP0 = *(const float4*)(aSrc);
        float4 aP1 = *(const float4*)(aSrc + 16 * P);
        float4 aP2 = *(const float4*)(aSrc + 32 * P);
        float4 aP3 = *(const float4*)(aSrc + 48 * P);
        float4 wP0 = *(const float4*)(wSrc);
        float4 wP1 = *(const float4*)(wSrc + 16 * 32);
        float4 acc0 = {0.f,0.f,0.f,0.f}, acc1 = {0.f,0.f,0.f,0.f};
        float4 acc2 = {0.f,0.f,0.f,0.f}, acc3 = {0.f,0.f,0.f,0.f};

        for (int kt = 0; kt < 32; ++kt) {
            __syncthreads();
            *(float4*)(sA + (arow +  0) * SPAD + aseg * 4) = aP0;
            *(float4*)(sA + (arow + 16) * SPAD + aseg * 4) = aP1;
            *(float4*)(sA + (arow + 32) * SPAD + aseg * 4) = aP2;
            *(float4*)(sA + (arow + 48) * SPAD + aseg * 4) = aP3;
            *(float4*)(sW + arow * 32 + aseg * 4) = wP0;
            *(float4*)(sW + (arow + 16) * 32 + aseg * 4) = wP1;
            __syncthreads();
            if (kt < 31) {
                const int ko = (kt + 1) * 32;
                aP0 = *(const float4*)(aSrc + ko);
                aP1 = *(const float4*)(aSrc + 16 * P + ko);
                aP2 = *(const float4*)(aSrc + 32 * P + ko);
                aP3 = *(const float4*)(aSrc + 48 * P + ko);
                wP0 = *(const float4*)(wSrc + (kt + 1) * 1024);
                wP1 = *(const float4*)(wSrc + 16 * 32 + (kt + 1) * 1024);
            }
            #pragma unroll
            for (int k4 = 0; k4 < 8; ++k4) {
                const float4 a0 = *(const float4*)(sA + (rg +  0) * SPAD + k4 * 4);
                const float4 a1 = *(const float4*)(sA + (rg + 16) * SPAD + k4 * 4);
                const float4 a2 = *(const float4*)(sA + (rg + 32) * SPAD + k4 * 4);
                const float4 a3 = *(const float4*)(sA + (rg + 48) * SPAD + k4 * 4);
                const float4 w0 = *(const float4*)(sW + (k4 * 4 + 0) * 32 + c0);
                const float4 w1 = *(const float4*)(sW + (k4 * 4 + 1) * 32 + c0);
                const float4 w2 = *(const float4*)(sW + (k4 * 4 + 2) * 32 + c0);
                const float4 w3 = *(const float4*)(sW + (k4 * 4 + 3) * 32 + c0);
                FMA4(acc0, a0, w0, w1, w2, w3);
                FMA4(acc1, a1, w0, w1, w2, w3);
                FMA4(acc2, a2, w0, w1, w2, w3);
                FMA4(acc3, a3, w0, w1, w2, w3);
            }
        }
        // layer 2: t1 = relu(acc + b1) -> sA; pol_w2 -> sW
        __syncthreads();
        {
            const float4 b1v = *(const float4*)(pol_b1 + c0);
            float4 t0, t1, t2, t3;
            t0.x = fmaxf(acc0.x + b1v.x, 0.f); t0.y = fmaxf(acc0.y + b1v.y, 0.f);
            t0.z = fmaxf(acc0.z + b1v.z, 0.f); t0.w = fmaxf(acc0.w + b1v.w, 0.f);
            t1.x = fmaxf(acc1.x + b1v.x, 0.f); t1.y = fmaxf(acc1.y + b1v.y, 0.f);
            t1.z = fmaxf(acc1.z + b1v.z, 0.f); t1.w = fmaxf(acc1.w + b1v.w, 0.f);
            t2.x = fmaxf(acc2.x + b1v.x, 0.f); t2.y = fmaxf(acc2.y + b1v.y, 0.f);
            t2.z = fmaxf(acc2.z + b1v.z, 0.f); t2.w = fmaxf(acc2.w + b1v.w, 0.f);
            t3.x = fmaxf(acc3.x + b1v.x, 0.f); t3.y = fmaxf(acc3.y + b1v.y, 0.f);
            t3.z = fmaxf(acc3.z + b1v.z, 0.f); t3.w = fmaxf(acc3.w + b1v.w, 0.f);
            *(float4*)(sA + (rg +  0) * SPAD + c0) = t0;
            *(float4*)(sA + (rg + 16) * SPAD + c0) = t1;
            *(float4*)(sA + (rg + 32) * SPAD + c0) = t2;
            *(float4*)(sA + (rg + 48) * SPAD + c0) = t3;
        }
        *(float4*)(sW + t * 4) = *(const float4*)(pol_w2 + t * 4);
        *(float4*)(sW + 512 + t * 4) = *(const float4*)(pol_w2 + 512 + t * 4);
        __syncthreads();

        float4 d0 = {0.f,0.f,0.f,0.f}, d1 = {0.f,0.f,0.f,0.f};
        float4 d2 = {0.f,0.f,0.f,0.f}, d3 = {0.f,0.f,0.f,0.f};
        #pragma unroll
        for (int k4 = 0; k4 < 8; ++k4) {
            const float4 a0 = *(const float4*)(sA + (rg +  0) * SPAD + k4 * 4);
            const float4 a1 = *(const float4*)(sA + (rg + 16) * SPAD + k4 * 4);
            const float4 a2 = *(const float4*)(sA + (rg + 32) * SPAD + k4 * 4);
            const float4 a3 = *(const float4*)(sA + (rg + 48) * SPAD + k4 * 4);
            const float4 w0 = *(const float4*)(sW + (k4 * 4 + 0) * 32 + c0);
            const float4 w1 = *(const float4*)(sW + (k4 * 4 + 1) * 32 + c0);
            const float4 w2 = *(const float4*)(sW + (k4 * 4 + 2) * 32 + c0);
            const float4 w3 = *(const float4*)(sW + (k4 * 4 + 3) * 32 + c0);
            FMA4(d0, a0, w0, w1, w2, w3);
            FMA4(d1, a1, w0, w1, w2, w3);
            FMA4(d2, a2, w0, w1, w2, w3);
            FMA4(d3, a3, w0, w1, w2, w3);
        }
        const float4 b2v = *(const float4*)(pol_b2 + c0);
        float4 o;
        o.x = fmaxf(d0.x + b2v.x, 0.f); o.y = fmaxf(d0.y + b2v.y, 0.f);
        o.z = fmaxf(d0.z + b2v.z, 0.f); o.w = fmaxf(d0.w + b2v.w, 0.f);
        *(float4*)(h1h2 + (r0 + rg +  0) * 96 + 64 + c0) = o;
        o.x = fmaxf(d1.x + b2v.x, 0.f); o.y = fmaxf(d1.y + b2v.y, 0.f);
        o.z = fmaxf(d1.z + b2v.z, 0.f); o.w = fmaxf(d1.w + b2v.w, 0.f);
        *(float4*)(h1h2 + (r0 + rg + 16) * 96 + 64 + c0) = o;
        o.x = fmaxf(d2.x + b2v.x, 0.f); o.y = fmaxf(d2.y + b2v.y, 0.f);
        o.z = fmaxf(d2.z + b2v.z, 0.f); o.w = fmaxf(d2.w + b2v.w, 0.f);
        *(float4*)(h1h2 + (r0 + rg + 32) * 96 + 64 + c0) = o;
        o.x = fmaxf(d3.x + b2v.x, 0.f); o.y = fmaxf(d3.y + b2v.y, 0.f);
        o.z = fmaxf(d3.z + b2v.z, 0.f); o.w = fmaxf(d3.w + b2v.w, 0.f);
        *(float4*)(h1h2 + (r0 + rg + 48) * 96 + 64 + c0) = o;
    } else {
        // ---- h1: 32 rows x 64 cols, K=512 in 16 tiles of 32.
        float* sA = smem;                 // [32][SPAD]
        float* sW = smem + 32 * SPAD;     // [32][64]
        const long r0 = (long)(bid - 672) * 32;
        const int c0 = (t & 15) * 4;
        const int rg = t >> 4;            // 0..7; rows rg + {0,8,16,24}
        const int arow = t >> 3, aseg = t & 7;       // A staging: i = t, t+128
        const int wrow = t >> 4, wseg = t & 15;      // W staging: i = t + 128q
        const float* aSrc = encoding + (r0 + arow) * IN_DIM + aseg * 4;
        const float* wSrc = enc_w1 + wrow * 64 + wseg * 4;

        float4 aP0 = *(const float4*)(aSrc);
        float4 aP1 = *(const float4*)(aSrc + 16 * IN_DIM);
        float4 wP0 = *(const float4*)(wSrc);
        float4 wP1 = *(const float4*)(wSrc + 8 * 64);
        float4 wP2 = *(const float4*)(wSrc + 16 * 64);
        float4 wP3 = *(const float4*)(wSrc + 24 * 64);
        float4 acc0 = {0.f,0.f,0.f,0.f}, acc1 = {0.f,0.f,0.f,0.f};
        float4 acc2 = {0.f,0.f,0.f,0.f}, acc3 = {0.f,0.f,0.f,0.f};

        for (int kt = 0; kt < 16; ++kt) {
            __syncthreads();
            *(float4*)(sA + arow * SPAD + aseg * 4) = aP0;
            *(float4*)(sA + (arow + 16) * SPAD + aseg * 4) = aP1;
            *(float4*)(sW + wrow * 64 + wseg * 4) = wP0;
            *(float4*)(sW + (wrow +  8) * 64 + wseg * 4) = wP1;
            *(float4*)(sW + (wrow + 16) * 64 + wseg * 4) = wP2;
            *(float4*)(sW + (wrow + 24) * 64 + wseg * 4) = wP3;
            __syncthreads();
            if (kt < 15) {
                const int ko = (kt + 1) * 32;
                aP0 = *(const float4*)(aSrc + ko);
                aP1 = *(const float4*)(aSrc + 16 * IN_DIM + ko);
                wP0 = *(const float4*)(wSrc + (kt + 1) * 2048);
                wP1 = *(const float4*)(wSrc +  8 * 64 + (kt + 1) * 2048);
                wP2 = *(const float4*)(wSrc + 16 * 64 + (kt + 1) * 2048);
                wP3 = *(const float4*)(wSrc + 24 * 64 + (kt + 1) * 2048);
            }
            #pragma unroll
            for (int k4 = 0; k4 < 8; ++k4) {
                const float4 a0 = *(const float4*)(sA + (rg +  0) * SPAD + k4 * 4);
                const float4 a1 = *(const float4*)(sA + (rg +  8) * SPAD + k4 * 4);
                const float4 a2 = *(const float4*)(sA + (rg + 16) * SPAD + k4 * 4);
                const float4 a3 = *(const float4*)(sA + (rg + 24) * SPAD + k4 * 4);
                const float4 w0 = *(const float4*)(sW + (k4 * 4 + 0) * 64 + c0);
                const float4 w1 = *(const float4*)(sW + (k4 * 4 + 1) * 64 + c0);
                const float4 w2 = *(const float4*)(sW + (k4 * 4 + 2) * 64 + c0);
                const float4 w3 = *(const float4*)(sW + (k4 * 4 + 3) * 64 + c0);
                FMA4(acc0, a0, w0, w1, w2, w3);
                FMA4(acc1, a1, w0, w1, w2, w3);
                FMA4(acc2, a2, w0, w1, w2, w3);
                FMA4(acc3, a3, w0, w1, w2, w3);
            }
        }
        float4 o;
        o.x = fmaxf(acc0.x, 0.f); o.y = fmaxf(acc0.y, 0.f);
        o.z = fmaxf(acc0.z, 0.f); o.w = fmaxf(acc0.w, 0.f);
        *(float4*)(h1h2 + (r0 + rg +  0) * 96 + c0) = o;
        o.x = fmaxf(acc1.x, 0.f); o.y = fmaxf(acc1.y, 0.f);
        o.z = fmaxf(acc1.z, 0.f); o.w = fmaxf(acc1.w, 0.f);
        *(float4*)(h1h2 + (r0 + rg +  8) * 96 + c0) = o;
        o.x = fmaxf(acc2.x, 0.f); o.y = fmaxf(acc2.y, 0.f);
        o.z = fmaxf(acc2.z, 0.f); o.w = fmaxf(acc2.w, 0.f);
        *(float4*)(h1h2 + (r0 + rg + 16) * 96 + c0) = o;
        o.x = fmaxf(acc3.x, 0.f); o.y = fmaxf(acc3.y, 0.f);
        o.z = fmaxf(acc3.z, 0.f); o.w = fmaxf(acc3.w, 0.f);
        *(float4*)(h1h2 + (r0 + rg + 24) * 96 + c0) = o;
    }
}

// ---------------------------------------------------------------------------
// logits + epilogue, readlane edition. Block = 8 rows x 1024 cols (2048 blocks);
// thread = 8 rows x 4 cols. h[8][96] lives distributed in VGPRs: lane (r + 8g)
// holds h[r][12g .. 12g+11] (3 float4, loaded direct from global). Broadcast via
// v_readlane -> SGPR FMA operand; k4 loop fully unrolled so lane idx is const.
// No LDS in the GEMM, no atomics (full row per block).
// ---------------------------------------------------------------------------
__device__ __forceinline__ float bcast(float v, int l) {
    return __int_as_float(__builtin_amdgcn_readlane(__float_as_int(v), l));
}

__global__ __launch_bounds__(256) void logits_ep(
    const float* __restrict__ h1h2,    // [N][96]
    const float* __restrict__ fused,   // [97][1024]
    const float* __restrict__ eps,     // [N][1024]
    float* __restrict__ out_sample,    // [N][1024]
    float* __restrict__ out_logprob,   // [N]
    float* __restrict__ out_entropy)   // [N]
{
    __shared__ float s_red[8][4];
    const int t = threadIdx.x;
    const long r0 = (long)blockIdx.x * 8;
    const int lane = t & 63;
    const int r_l = lane & 7, g_l = lane >> 3;   // lane holds h[r_l][12*g_l .. +11]

    const float* hsrc = h1h2 + (r0 + r_l) * 96 + g_l * 12;
    const float4 hA = *(const float4*)(hsrc);
    const float4 hB = *(const float4*)(hsrc + 4);
    const float4 hC = *(const float4*)(hsrc + 8);

    const int j0 = t * 4;
    const float* fj = fused + j0;

    float4 acc[8];
    {
        const float4 b = *(const float4*)(fj + 96 * 1024);
        #pragma unroll
        for (int r = 0; r < 8; ++r) acc[r] = b;
    }

    #pragma unroll
    for (int k4 = 0; k4 < 24; ++k4) {
        const float4 w0 = *(const float4*)(fj + (size_t)(k4 * 4 + 0) * 1024);
        const float4 w1 = *(const float4*)(fj + (size_t)(k4 * 4 + 1) * 1024);
        const float4 w2 = *(const float4*)(fj + (size_t)(k4 * 4 + 2) * 1024);
        const float4 w3 = *(const float4*)(fj + (size_t)(k4 * 4 + 3) * 1024);
        const int g = k4 / 3;        // source lane group (compile-time)
        const int m = k4 % 3;        // which float4 (compile-time)
        #pragma unroll
        for (int r = 0; r < 8; ++r) {
            const int sl = g * 8 + r;
            float hx, hy, hz, hw;
            if (m == 0)      { hx = bcast(hA.x, sl); hy = bcast(hA.y, sl);
                               hz = bcast(hA.z, sl); hw = bcast(hA.w, sl); }
            else if (m == 1) { hx = bcast(hB.x, sl); hy = bcast(hB.y, sl);
                               hz = bcast(hB.z, sl); hw = bcast(hB.w, sl); }
            else             { hx = bcast(hC.x, sl); hy = bcast(hC.y, sl);
                               hz = bcast(hC.z, sl); hw = bcast(hC.w, sl); }
            acc[r].x = fmaf(hx, w0.x, acc[r].x);
            acc[r].y = fmaf(hx, w0.y, acc[r].y);
            acc[r].z = fmaf(hx, w0.z, acc[r].z);
            acc[r].w = fmaf(hx, w0.w, acc[r].w);
            acc[r].x = fmaf(hy, w1.x, acc[r].x);
            acc[r].y = fmaf(hy, w1.y, acc[r].y);
            acc[r].z = fmaf(hy, w1.z, acc[r].z);
            acc[r].w = fmaf(hy, w1.w, acc[r].w);
            acc[r].x = fmaf(hz, w2.x, acc[r].x);
            acc[r].y = fmaf(hz, w2.y, acc[r].y);
            acc[r].z = fmaf(hz, w2.z, acc[r].z);
            acc[r].w = fmaf(hz, w2.w, acc[r].w);
            acc[r].x = fmaf(hw, w3.x, acc[r].x);
            acc[r].y = fmaf(hw, w3.y, acc[r].y);
            acc[r].z = fmaf(hw, w3.z, acc[r].z);
            acc[r].w = fmaf(hw, w3.w, acc[r].w);
        }
    }

    float sq[8];
    const float* ep = eps + r0 * P + j0;
    float* sp = out_sample + r0 * P + j0;
    #pragma unroll
    for (int r = 0; r < 8; ++r) {
        const float m0 = 1.f / (1.f + __expf(-acc[r].x));
        const float m1 = 1.f / (1.f + __expf(-acc[r].y));
        const float m2 = 1.f / (1.f + __expf(-acc[r].z));
        const float m3 = 1.f / (1.f + __expf(-acc[r].w));
        const float4 e = *(const float4*)(ep + r * P);
        const float s0 = fminf(fmaxf(fmaf(0.22360679774997896f, e.x, m0), 0.f), 1.f);
        const float s1 = fminf(fmaxf(fmaf(0.22360679774997896f, e.y, m1), 0.f), 1.f);
        const float s2 = fminf(fmaxf(fmaf(0.22360679774997896f, e.z, m2), 0.f), 1.f);
        const float s3 = fminf(fmaxf(fmaf(0.22360679774997896f, e.w, m3), 0.f), 1.f);
        *(float4*)(sp + r * P) = make_float4(s0, s1, s2, s3);
        const float d0 = s0 - m0, d1 = s1 - m1, d2 = s2 - m2, d3 = s3 - m3;
        sq[r] = fmaf(d0, d0, fmaf(d1, d1, fmaf(d2, d2, d3 * d3)));
    }
    #pragma unroll
    for (int r = 0; r < 8; ++r) {
        float v = sq[r];
        v += __shfl_xor(v, 1);
        v += __shfl_xor(v, 2);
        v += __shfl_xor(v, 4);
        v += __shfl_xor(v, 8);
        v += __shfl_xor(v, 16);
        v += __shfl_xor(v, 32);
        if ((t & 63) == 0) s_red[r][t >> 6] = v;
    }
    __syncthreads();
    if (t < 8) {
        const float v = s_red[t][0] + s_red[t][1] + s_red[t][2] + s_red[t][3];
        out_logprob[r0 + t] = fmaf(-10.f, v, 592.8218660580586f);
        out_entropy[r0 + t] = -80.82186605805855f;
    }
}

extern "C" void kernel_launch(void* const* d_in, const int* in_sizes, int n_in,
                              void* d_out, int out_size, void* d_ws, size_t ws_size,
                              hipStream_t stream) {
    const float* encoding = (const float*)d_in[0];
    const float* mean     = (const float*)d_in[1];
    const float* enc_w1   = (const float*)d_in[2];
    const float* enc_w2   = (const float*)d_in[3];
    const float* pol_w1   = (const float*)d_in[4];
    const float* pol_b1   = (const float*)d_in[5];
    const float* pol_w2   = (const float*)d_in[6];
    const float* pol_b2   = (const float*)d_in[7];
    const float* pol_w3   = (const float*)d_in[8];
    const float* pol_b3   = (const float*)d_in[9];
    const float* comb_w   = (const float*)d_in[10];
    const float* comb_b   = (const float*)d_in[11];
    const float* eps      = (const float*)d_in[12];

    float* fused = (float*)d_ws;                          // 97*1024 floats
    float* h1h2  = fused + 97 * 1024;                     // 16384*96 floats
    float* out_sample  = (float*)d_out;
    float* out_logprob = out_sample + (size_t)N_CLIENTS * P;
    float* out_entropy = out_logprob + N_CLIENTS;

    hipMemsetAsync(fused, 0, 97 * 1024 * sizeof(float), stream);

    stage1<<<1184, 128, 0, stream>>>(encoding, mean, enc_w1, pol_w1, pol_b1,
                                     pol_w2, pol_b2, enc_w2, pol_w3, pol_b3,
                                     comb_w, comb_b, h1h2, fused);

    logits_ep<<<N_CLIENTS / 8, 256, 0, stream>>>(
        h1h2, fused, eps, out_sample, out_logprob, out_entropy);
}